// Round 1
// baseline (30.520 us; speedup 1.0000x reference)
//
#include <hip/hip_runtime.h>

// out[z,k] = sum_{i,j} C[k,i,j] * f1[z,i] * f2[z,j]
// Z=4096, K=3600, I=J=60, all fp32.
//
// Key structure: C[k,:,:] is nonzero only inside ONE d1 x d2 sub-block
// (d1,d2 <= 5), derivable from k via the (l1,l2,l,u,v,m) block decomposition
// of RS1=RS2=[(16,0),(8,1),(4,2)]. We hardcode the 19 (l1,l2,l) segments.

#define ZT    32     // z rows per block
#define NF    60     // feature dim
#define KTOT  3600   // output channels
#define BLOCK 256

struct Seg { short kstart, mul2, dl, d1, d2, ioff, joff; };

// Segments in build_mixing_matrix loop order; entry 19 is a sentinel.
__constant__ Seg c_segs[20] = {
  {   0,16,1,1,1, 0, 0},  // (l1=0,l2=0,l=0)
  { 256, 8,3,1,3, 0,16},  // (0,1,1)
  { 640, 4,5,1,5, 0,40},  // (0,2,2)
  { 960,16,3,3,1,16, 0},  // (1,0,1)
  {1344, 8,1,3,3,16,16},  // (1,1,0)
  {1408, 8,3,3,3,16,16},  // (1,1,1)
  {1600, 8,5,3,3,16,16},  // (1,1,2)
  {1920, 4,3,3,5,16,40},  // (1,2,1)
  {2016, 4,5,3,5,16,40},  // (1,2,2)
  {2176, 4,7,3,5,16,40},  // (1,2,3)
  {2400,16,5,5,1,40, 0},  // (2,0,2)
  {2720, 8,3,5,3,40,16},  // (2,1,1)
  {2816, 8,5,5,3,40,16},  // (2,1,2)
  {2976, 8,7,5,3,40,16},  // (2,1,3)
  {3200, 4,1,5,5,40,40},  // (2,2,0)
  {3216, 4,3,5,5,40,40},  // (2,2,1)
  {3264, 4,5,5,5,40,40},  // (2,2,2)
  {3344, 4,7,5,5,40,40},  // (2,2,3)
  {3456, 4,9,5,5,40,40},  // (2,2,4)
  {3600, 0,1,1,1, 0, 0}   // sentinel
};

// Compile-time (D1,D2) so every array index is static -> registers, no scratch.
template<int D1, int D2>
__device__ __forceinline__ void tp_body(const float* __restrict__ Crow,
    int i0, int j0,
    const float (&f1s)[ZT][NF], const float (&f2s)[ZT][NF],
    float* __restrict__ out, int k, int z0)
{
  float c[D1 * D2];
#pragma unroll
  for (int ii = 0; ii < D1; ++ii)
#pragma unroll
    for (int jj = 0; jj < D2; ++jj)
      c[ii * D2 + jj] = Crow[(i0 + ii) * NF + (j0 + jj)];

#pragma unroll 2
  for (int zz = 0; zz < ZT; ++zz) {
    float r1[D1], r2[D2];
#pragma unroll
    for (int ii = 0; ii < D1; ++ii) r1[ii] = f1s[zz][i0 + ii];
#pragma unroll
    for (int jj = 0; jj < D2; ++jj) r2[jj] = f2s[zz][j0 + jj];
    float acc = 0.f;
#pragma unroll
    for (int ii = 0; ii < D1; ++ii)
#pragma unroll
      for (int jj = 0; jj < D2; ++jj)
        acc = fmaf(c[ii * D2 + jj], r1[ii] * r2[jj], acc);
    out[(size_t)(z0 + zz) * KTOT + k] = acc;
  }
}

__global__ __launch_bounds__(BLOCK) void tp_kernel(
    const float* __restrict__ f1, const float* __restrict__ f2,
    const float* __restrict__ M, float* __restrict__ out)
{
  __shared__ float f1s[ZT][NF];
  __shared__ float f2s[ZT][NF];
  const int z0 = blockIdx.y * ZT;

  // Coalesced flat copy of the two 32x60 feature tiles into LDS.
  const float* f1p = f1 + (size_t)z0 * NF;
  const float* f2p = f2 + (size_t)z0 * NF;
  for (int idx = threadIdx.x; idx < ZT * NF; idx += BLOCK) {
    (&f1s[0][0])[idx] = f1p[idx];
    (&f2s[0][0])[idx] = f2p[idx];
  }
  __syncthreads();

  const int k = blockIdx.x * BLOCK + (int)threadIdx.x;
  if (k >= KTOT) return;

  // Locate segment (19 entries, mostly wave-uniform).
  int s = 0;
#pragma unroll 1
  while (k >= c_segs[s + 1].kstart) ++s;
  const Seg sg = c_segs[s];

  const int local = k - sg.kstart;
  const int uv = local / sg.dl;          // (u*mul2 + v)
  const int u  = uv / sg.mul2;
  const int v  = uv - u * sg.mul2;
  const int i0 = sg.ioff + u * sg.d1;
  const int j0 = sg.joff + v * sg.d2;
  const float* Crow = M + (size_t)k * (NF * NF);

  if (sg.d1 == 1) {
    if (sg.d2 == 1)      tp_body<1,1>(Crow, i0, j0, f1s, f2s, out, k, z0);
    else if (sg.d2 == 3) tp_body<1,3>(Crow, i0, j0, f1s, f2s, out, k, z0);
    else                 tp_body<1,5>(Crow, i0, j0, f1s, f2s, out, k, z0);
  } else if (sg.d1 == 3) {
    if (sg.d2 == 1)      tp_body<3,1>(Crow, i0, j0, f1s, f2s, out, k, z0);
    else if (sg.d2 == 3) tp_body<3,3>(Crow, i0, j0, f1s, f2s, out, k, z0);
    else                 tp_body<3,5>(Crow, i0, j0, f1s, f2s, out, k, z0);
  } else {
    if (sg.d2 == 1)      tp_body<5,1>(Crow, i0, j0, f1s, f2s, out, k, z0);
    else if (sg.d2 == 3) tp_body<5,3>(Crow, i0, j0, f1s, f2s, out, k, z0);
    else                 tp_body<5,5>(Crow, i0, j0, f1s, f2s, out, k, z0);
  }
}

extern "C" void kernel_launch(void* const* d_in, const int* in_sizes, int n_in,
                              void* d_out, int out_size, void* d_ws, size_t ws_size,
                              hipStream_t stream) {
  const float* f1 = (const float*)d_in[0];
  const float* f2 = (const float*)d_in[1];
  const float* M  = (const float*)d_in[2];
  float* out = (float*)d_out;

  const int Z = in_sizes[0] / NF;        // 4096
  dim3 grid((KTOT + BLOCK - 1) / BLOCK,  // 15
            Z / ZT);                     // 128
  tp_kernel<<<grid, dim3(BLOCK), 0, stream>>>(f1, f2, M, out);
}

// Round 2
// 27.584 us; speedup vs baseline: 1.1064x; 1.1064x over previous
//
#include <hip/hip_runtime.h>

// out[z,k] = sum_{i,j} C[k,i,j] * f1[z,i] * f2[z,j]
// Z=4096, K=3600, I=J=60, all fp32.
//
// C[k,:,:] is nonzero only inside ONE d1 x d2 sub-block (d1,d2 <= 5),
// derivable from k via the (l1,l2,l,u,v,m) block decomposition of
// RS1=RS2=[(16,0),(8,1),(4,2)]. Hardcoded 19 (l1,l2,l) segments.
//
// This version: feature-major LDS tiles (f1s[feat][z], pad->stride 36 keeps
// ds_read_b128 alignment + conflict-free read banks), z processed in chunks
// of 4 via one b128 per operand row, and factored bilinear form
// (d1*d2 + min(d1,d2) fma instead of 2*d1*d2 ops).

#define ZT    32     // z rows per block
#define ZPAD  36     // row stride (floats): 16B-aligned b128, banks spread by i mod 8
#define NF    60     // feature dim
#define KTOT  3600   // output channels
#define BLOCK 256

typedef float f32x4 __attribute__((ext_vector_type(4)));

struct Seg { short kstart, mul2, dl, d1, d2, ioff, joff; };

__constant__ Seg c_segs[20] = {
  {   0,16,1,1,1, 0, 0},  // (l1=0,l2=0,l=0)
  { 256, 8,3,1,3, 0,16},  // (0,1,1)
  { 640, 4,5,1,5, 0,40},  // (0,2,2)
  { 960,16,3,3,1,16, 0},  // (1,0,1)
  {1344, 8,1,3,3,16,16},  // (1,1,0)
  {1408, 8,3,3,3,16,16},  // (1,1,1)
  {1600, 8,5,3,3,16,16},  // (1,1,2)
  {1920, 4,3,3,5,16,40},  // (1,2,1)
  {2016, 4,5,3,5,16,40},  // (1,2,2)
  {2176, 4,7,3,5,16,40},  // (1,2,3)
  {2400,16,5,5,1,40, 0},  // (2,0,2)
  {2720, 8,3,5,3,40,16},  // (2,1,1)
  {2816, 8,5,5,3,40,16},  // (2,1,2)
  {2976, 8,7,5,3,40,16},  // (2,1,3)
  {3200, 4,1,5,5,40,40},  // (2,2,0)
  {3216, 4,3,5,5,40,40},  // (2,2,1)
  {3264, 4,5,5,5,40,40},  // (2,2,2)
  {3344, 4,7,5,5,40,40},  // (2,2,3)
  {3456, 4,9,5,5,40,40},  // (2,2,4)
  {3600, 0,1,1,1, 0, 0}   // sentinel
};

template<int D1, int D2>
__device__ __forceinline__ void tp_body(const float* __restrict__ Crow,
    int i0, int j0,
    const float (&f1s)[NF][ZPAD], const float (&f2s)[NF][ZPAD],
    float* __restrict__ out, int k, int z0)
{
  float c[D1 * D2];
#pragma unroll
  for (int ii = 0; ii < D1; ++ii)
#pragma unroll
    for (int jj = 0; jj < D2; ++jj)
      c[ii * D2 + jj] = Crow[(i0 + ii) * NF + (j0 + jj)];

  float* op = out + (size_t)z0 * KTOT + k;

#pragma unroll 1
  for (int zz = 0; zz < ZT; zz += 4) {
    f32x4 a[D1], b[D2];
#pragma unroll
    for (int ii = 0; ii < D1; ++ii)
      a[ii] = *(const f32x4*)&f1s[i0 + ii][zz];
#pragma unroll
    for (int jj = 0; jj < D2; ++jj)
      b[jj] = *(const f32x4*)&f2s[j0 + jj][zz];

    float* opz = op + (size_t)zz * KTOT;
#pragma unroll
    for (int q = 0; q < 4; ++q) {
      float acc = 0.f;
      if constexpr (D1 <= D2) {
#pragma unroll
        for (int ii = 0; ii < D1; ++ii) {
          float t = 0.f;
#pragma unroll
          for (int jj = 0; jj < D2; ++jj)
            t = fmaf(c[ii * D2 + jj], b[jj][q], t);
          acc = fmaf(t, a[ii][q], acc);
        }
      } else {
#pragma unroll
        for (int jj = 0; jj < D2; ++jj) {
          float t = 0.f;
#pragma unroll
          for (int ii = 0; ii < D1; ++ii)
            t = fmaf(c[ii * D2 + jj], a[ii][q], t);
          acc = fmaf(t, b[jj][q], acc);
        }
      }
      opz[(size_t)q * KTOT] = acc;
    }
  }
}

__global__ __launch_bounds__(BLOCK) void tp_kernel(
    const float* __restrict__ f1, const float* __restrict__ f2,
    const float* __restrict__ M, float* __restrict__ out)
{
  __shared__ __align__(16) float f1s[NF][ZPAD];
  __shared__ __align__(16) float f2s[NF][ZPAD];
  const int z0 = blockIdx.y * ZT;

  // Coalesced float4 global reads, transposed scalar LDS writes.
  // 32*60/4 = 480 float4 per tile; NF=60 divisible by 4 so each float4
  // stays within one z-row (z = t*4/60, f0 = t*4%60).
  {
    const float* f1p = f1 + (size_t)z0 * NF;
    const float* f2p = f2 + (size_t)z0 * NF;
    for (int t = threadIdx.x; t < (ZT * NF) / 4; t += BLOCK) {
      f32x4 v = *(const f32x4*)(f1p + t * 4);
      int zz = (t * 4) / NF;
      int f0 = (t * 4) % NF;
      f1s[f0 + 0][zz] = v[0]; f1s[f0 + 1][zz] = v[1];
      f1s[f0 + 2][zz] = v[2]; f1s[f0 + 3][zz] = v[3];
    }
    for (int t = threadIdx.x; t < (ZT * NF) / 4; t += BLOCK) {
      f32x4 v = *(const f32x4*)(f2p + t * 4);
      int zz = (t * 4) / NF;
      int f0 = (t * 4) % NF;
      f2s[f0 + 0][zz] = v[0]; f2s[f0 + 1][zz] = v[1];
      f2s[f0 + 2][zz] = v[2]; f2s[f0 + 3][zz] = v[3];
    }
  }
  __syncthreads();

  const int k = blockIdx.x * BLOCK + (int)threadIdx.x;
  if (k >= KTOT) return;

  // Locate segment (19 entries; runs once per thread).
  int s = 0;
#pragma unroll 1
  while (k >= c_segs[s + 1].kstart) ++s;
  const Seg sg = c_segs[s];

  const int local = k - sg.kstart;
  const int uv = local / sg.dl;          // (u*mul2 + v)
  const int u  = uv / sg.mul2;
  const int v  = uv - u * sg.mul2;
  const int i0 = sg.ioff + u * sg.d1;
  const int j0 = sg.joff + v * sg.d2;
  const float* Crow = M + (size_t)k * (NF * NF);

  if (sg.d1 == 1) {
    if (sg.d2 == 1)      tp_body<1,1>(Crow, i0, j0, f1s, f2s, out, k, z0);
    else if (sg.d2 == 3) tp_body<1,3>(Crow, i0, j0, f1s, f2s, out, k, z0);
    else                 tp_body<1,5>(Crow, i0, j0, f1s, f2s, out, k, z0);
  } else if (sg.d1 == 3) {
    if (sg.d2 == 1)      tp_body<3,1>(Crow, i0, j0, f1s, f2s, out, k, z0);
    else if (sg.d2 == 3) tp_body<3,3>(Crow, i0, j0, f1s, f2s, out, k, z0);
    else                 tp_body<3,5>(Crow, i0, j0, f1s, f2s, out, k, z0);
  } else {
    if (sg.d2 == 1)      tp_body<5,1>(Crow, i0, j0, f1s, f2s, out, k, z0);
    else if (sg.d2 == 3) tp_body<5,3>(Crow, i0, j0, f1s, f2s, out, k, z0);
    else                 tp_body<5,5>(Crow, i0, j0, f1s, f2s, out, k, z0);
  }
}

extern "C" void kernel_launch(void* const* d_in, const int* in_sizes, int n_in,
                              void* d_out, int out_size, void* d_ws, size_t ws_size,
                              hipStream_t stream) {
  const float* f1 = (const float*)d_in[0];
  const float* f2 = (const float*)d_in[1];
  const float* M  = (const float*)d_in[2];
  float* out = (float*)d_out;

  const int Z = in_sizes[0] / NF;        // 4096
  dim3 grid((KTOT + BLOCK - 1) / BLOCK,  // 15
            Z / ZT);                     // 128
  tp_kernel<<<grid, dim3(BLOCK), 0, stream>>>(f1, f2, M, out);
}

// Round 3
// 25.611 us; speedup vs baseline: 1.1917x; 1.0770x over previous
//
#include <hip/hip_runtime.h>

// out[z,k] = sum_{i,j} C[k,i,j] * f1[z,i] * f2[z,j]
// Z=4096, K=3600, I=J=60, all fp32.
//
// C[k,:,:] is nonzero only inside ONE d1 x d2 sub-block (d1,d2 <= 5),
// derivable from k via the (l1,l2,l,u,v,m) block decomposition of
// RS1=RS2=[(16,0),(8,1),(4,2)]. 19 hardcoded (l1,l2,l) segments.
// All (l1,l2)-group boundaries are multiples of 64 -> no wave ever mixes
// (d1,d2) template bodies.
//
// Round 3: ZT=64 (2x startup amortization), branchless segment decode,
// c[] loads issued before the LDS-stage barrier (latency hidden), 2-deep
// ping-pong software pipeline over z-chunks, nontemporal output stores.

#define ZT    64     // z rows per block
#define ZPAD  68     // row stride (floats): 16B-aligned b128, conflict-free reads
#define NF    60     // feature dim
#define KTOT  3600   // output channels
#define BLOCK 256
#define NLD   ((ZT * NF) / 4)   // 960 float4 per feature tile

typedef float f32x4 __attribute__((ext_vector_type(4)));

struct Seg { short kstart, mul2, dl, d1, d2, ioff, joff, pad; };

__constant__ Seg c_segs[19] = {
  {   0,16,1,1,1, 0, 0,0},  // (0,0,0)
  { 256, 8,3,1,3, 0,16,0},  // (0,1,1)
  { 640, 4,5,1,5, 0,40,0},  // (0,2,2)
  { 960,16,3,3,1,16, 0,0},  // (1,0,1)
  {1344, 8,1,3,3,16,16,0},  // (1,1,0)
  {1408, 8,3,3,3,16,16,0},  // (1,1,1)
  {1600, 8,5,3,3,16,16,0},  // (1,1,2)
  {1920, 4,3,3,5,16,40,0},  // (1,2,1)
  {2016, 4,5,3,5,16,40,0},  // (1,2,2)
  {2176, 4,7,3,5,16,40,0},  // (1,2,3)
  {2400,16,5,5,1,40, 0,0},  // (2,0,2)
  {2720, 8,3,5,3,40,16,0},  // (2,1,1)
  {2816, 8,5,5,3,40,16,0},  // (2,1,2)
  {2976, 8,7,5,3,40,16,0},  // (2,1,3)
  {3200, 4,1,5,5,40,40,0},  // (2,2,0)
  {3216, 4,3,5,5,40,40,0},  // (2,2,1)
  {3264, 4,5,5,5,40,40,0},  // (2,2,2)
  {3344, 4,7,5,5,40,40,0},  // (2,2,3)
  {3456, 4,9,5,5,40,40,0}   // (2,2,4)
};

template<int D1, int D2>
__device__ __forceinline__ void load_c(float (&c)[25],
    const float* __restrict__ Crow, int i0, int j0)
{
#pragma unroll
  for (int ii = 0; ii < D1; ++ii)
#pragma unroll
    for (int jj = 0; jj < D2; ++jj)
      c[ii * D2 + jj] = Crow[(i0 + ii) * NF + (j0 + jj)];
}

template<int D1, int D2>
__device__ __forceinline__ void ld_ab(f32x4 (&a)[D1], f32x4 (&b)[D2],
    const float (&f1s)[NF][ZPAD], const float (&f2s)[NF][ZPAD],
    int i0, int j0, int zz)
{
#pragma unroll
  for (int ii = 0; ii < D1; ++ii) a[ii] = *(const f32x4*)&f1s[i0 + ii][zz];
#pragma unroll
  for (int jj = 0; jj < D2; ++jj) b[jj] = *(const f32x4*)&f2s[j0 + jj][zz];
}

template<int D1, int D2>
__device__ __forceinline__ void comp_st(const float (&c)[25],
    const f32x4 (&a)[D1], const f32x4 (&b)[D2], float* __restrict__ opz)
{
#pragma unroll
  for (int q = 0; q < 4; ++q) {
    float acc;
    if constexpr (D1 <= D2) {
      acc = 0.f;
#pragma unroll
      for (int ii = 0; ii < D1; ++ii) {
        float t = c[ii * D2] * b[0][q];
#pragma unroll
        for (int jj = 1; jj < D2; ++jj) t = fmaf(c[ii * D2 + jj], b[jj][q], t);
        acc = fmaf(t, a[ii][q], acc);
      }
    } else {
      acc = 0.f;
#pragma unroll
      for (int jj = 0; jj < D2; ++jj) {
        float t = c[jj] * a[0][q];
#pragma unroll
        for (int ii = 1; ii < D1; ++ii) t = fmaf(c[ii * D2 + jj], a[ii][q], t);
        acc = fmaf(t, b[jj][q], acc);
      }
    }
    __builtin_nontemporal_store(acc, opz + (size_t)q * KTOT);
  }
}

// 2-deep ping-pong pipeline: statically-named register sets (no dyn indexing).
template<int D1, int D2>
__device__ void tp_body(const float (&c)[25], int i0, int j0,
    const float (&f1s)[NF][ZPAD], const float (&f2s)[NF][ZPAD],
    float* __restrict__ op)     // = out + z0*KTOT + k
{
  f32x4 aA[D1], bA[D2], aB[D1], bB[D2];
  ld_ab<D1,D2>(aA, bA, f1s, f2s, i0, j0, 0);
#pragma unroll 1
  for (int zz = 0; zz < ZT; zz += 8) {
    ld_ab<D1,D2>(aB, bB, f1s, f2s, i0, j0, zz + 4);
    comp_st<D1,D2>(c, aA, bA, op + (size_t)zz * KTOT);
    if (zz + 8 < ZT) ld_ab<D1,D2>(aA, bA, f1s, f2s, i0, j0, zz + 8);
    comp_st<D1,D2>(c, aB, bB, op + (size_t)(zz + 4) * KTOT);
  }
}

__global__ __launch_bounds__(BLOCK, 3) void tp_kernel(
    const float* __restrict__ f1, const float* __restrict__ f2,
    const float* __restrict__ M, float* __restrict__ out)
{
  __shared__ __align__(16) float f1s[NF][ZPAD];
  __shared__ __align__(16) float f2s[NF][ZPAD];
  const int z0  = blockIdx.y * ZT;
  const int tid = (int)threadIdx.x;

  // (1) Issue feature-tile staging loads (coalesced float4) into registers.
  const float* f1p = f1 + (size_t)z0 * NF;
  const float* f2p = f2 + (size_t)z0 * NF;
  f32x4 s1[4], s2[4];
#pragma unroll
  for (int r = 0; r < 4; ++r) {
    int t = tid + r * BLOCK;
    if (t < NLD) {
      s1[r] = *(const f32x4*)(f1p + t * 4);
      s2[r] = *(const f32x4*)(f2p + t * 4);
    }
  }

  // (2) Branchless segment decode (compile-time kstart literals, ~18 VALU).
  const int k  = blockIdx.x * BLOCK + tid;
  const int kc = k < KTOT ? k : KTOT - 1;
  int s = 0;
  s += (kc >=  256); s += (kc >=  640); s += (kc >=  960); s += (kc >= 1344);
  s += (kc >= 1408); s += (kc >= 1600); s += (kc >= 1920); s += (kc >= 2016);
  s += (kc >= 2176); s += (kc >= 2400); s += (kc >= 2720); s += (kc >= 2816);
  s += (kc >= 2976); s += (kc >= 3200); s += (kc >= 3216); s += (kc >= 3264);
  s += (kc >= 3344); s += (kc >= 3456);
  const Seg sg = c_segs[s];
  const int local = kc - sg.kstart;
  const int uv = local / sg.dl;
  const int u  = uv / sg.mul2;
  const int v  = uv - u * sg.mul2;
  const int i0 = sg.ioff + u * sg.d1;
  const int j0 = sg.joff + v * sg.d2;
  const float* Crow = M + (size_t)kc * (NF * NF);

  // (3) Issue c[] loads NOW — latency rides through ds_write + barrier.
  float c[25];
  const int d1 = sg.d1, d2 = sg.d2;
  if (d1 == 1) {
    if (d2 == 1)      load_c<1,1>(c, Crow, i0, j0);
    else if (d2 == 3) load_c<1,3>(c, Crow, i0, j0);
    else              load_c<1,5>(c, Crow, i0, j0);
  } else if (d1 == 3) {
    if (d2 == 1)      load_c<3,1>(c, Crow, i0, j0);
    else if (d2 == 3) load_c<3,3>(c, Crow, i0, j0);
    else              load_c<3,5>(c, Crow, i0, j0);
  } else {
    if (d2 == 1)      load_c<5,1>(c, Crow, i0, j0);
    else if (d2 == 3) load_c<5,3>(c, Crow, i0, j0);
    else              load_c<5,5>(c, Crow, i0, j0);
  }

  // (4) Transposed LDS write (feature-major): f1s[f][z].
#pragma unroll
  for (int r = 0; r < 4; ++r) {
    int t = tid + r * BLOCK;
    if (t < NLD) {
      int g = t * 4, zz = g / NF, f0 = g % NF;
      f1s[f0 + 0][zz] = s1[r][0]; f1s[f0 + 1][zz] = s1[r][1];
      f1s[f0 + 2][zz] = s1[r][2]; f1s[f0 + 3][zz] = s1[r][3];
      f2s[f0 + 0][zz] = s2[r][0]; f2s[f0 + 1][zz] = s2[r][1];
      f2s[f0 + 2][zz] = s2[r][2]; f2s[f0 + 3][zz] = s2[r][3];
    }
  }
  __syncthreads();

  if (k >= KTOT) return;
  float* op = out + (size_t)z0 * KTOT + k;

  if (d1 == 1) {
    if (d2 == 1)      tp_body<1,1>(c, i0, j0, f1s, f2s, op);
    else if (d2 == 3) tp_body<1,3>(c, i0, j0, f1s, f2s, op);
    else              tp_body<1,5>(c, i0, j0, f1s, f2s, op);
  } else if (d1 == 3) {
    if (d2 == 1)      tp_body<3,1>(c, i0, j0, f1s, f2s, op);
    else if (d2 == 3) tp_body<3,3>(c, i0, j0, f1s, f2s, op);
    else              tp_body<3,5>(c, i0, j0, f1s, f2s, op);
  } else {
    if (d2 == 1)      tp_body<5,1>(c, i0, j0, f1s, f2s, op);
    else if (d2 == 3) tp_body<5,3>(c, i0, j0, f1s, f2s, op);
    else              tp_body<5,5>(c, i0, j0, f1s, f2s, op);
  }
}

extern "C" void kernel_launch(void* const* d_in, const int* in_sizes, int n_in,
                              void* d_out, int out_size, void* d_ws, size_t ws_size,
                              hipStream_t stream) {
  const float* f1 = (const float*)d_in[0];
  const float* f2 = (const float*)d_in[1];
  const float* M  = (const float*)d_in[2];
  float* out = (float*)d_out;

  const int Z = in_sizes[0] / NF;        // 4096
  dim3 grid((KTOT + BLOCK - 1) / BLOCK,  // 15
            Z / ZT);                     // 64
  tp_kernel<<<grid, dim3(BLOCK), 0, stream>>>(f1, f2, M, out);
}

// Round 4
// 24.599 us; speedup vs baseline: 1.2407x; 1.0411x over previous
//
#include <hip/hip_runtime.h>

// out[z,k] = sum_{i,j} C[k,i,j] * f1[z,i] * f2[z,j]
// Z=4096, K=3600, I=J=60, all fp32.
//
// C[k,:,:] is nonzero only inside ONE d1 x d2 sub-block (d1,d2 <= 5),
// derivable from k via the (l1,l2,l,u,v,m) block decomposition of
// RS1=RS2=[(16,0),(8,1),(4,2)]. 19 hardcoded (l1,l2,l) segments.
//
// Round 4: static load balancing. Per-k-wave cost (~d1+d2) varies 5x across
// the k spectrum; consecutive k-blocks previously landed on the same CU ->
// makespan bound. Each block now gets 4 k-waves chosen so every block's
// cost sums to exactly 24 (compile-time balanced partition of the 57
// k-waves; 3 dummy slots). Wave-uniform (d1,d2) preserved.

#define ZT    64     // z rows per block
#define ZPAD  68     // row stride (floats): 16B-aligned b128, spread read banks
#define NF    60     // feature dim
#define KTOT  3600   // output channels
#define BLOCK 256
#define NLD   ((ZT * NF) / 4)   // 960 float4 per feature tile

typedef float f32x4 __attribute__((ext_vector_type(4)));

struct Seg { short kstart, mul2, dl, d1, d2, ioff, joff, pad; };

__constant__ Seg c_segs[19] = {
  {   0,16,1,1,1, 0, 0,0},  // (0,0,0)
  { 256, 8,3,1,3, 0,16,0},  // (0,1,1)
  { 640, 4,5,1,5, 0,40,0},  // (0,2,2)
  { 960,16,3,3,1,16, 0,0},  // (1,0,1)
  {1344, 8,1,3,3,16,16,0},  // (1,1,0)
  {1408, 8,3,3,3,16,16,0},  // (1,1,1)
  {1600, 8,5,3,3,16,16,0},  // (1,1,2)
  {1920, 4,3,3,5,16,40,0},  // (1,2,1)
  {2016, 4,5,3,5,16,40,0},  // (1,2,2)
  {2176, 4,7,3,5,16,40,0},  // (1,2,3)
  {2400,16,5,5,1,40, 0,0},  // (2,0,2)
  {2720, 8,3,5,3,40,16,0},  // (2,1,1)
  {2816, 8,5,5,3,40,16,0},  // (2,1,2)
  {2976, 8,7,5,3,40,16,0},  // (2,1,3)
  {3200, 4,1,5,5,40,40,0},  // (2,2,0)
  {3216, 4,3,5,5,40,40,0},  // (2,2,1)
  {3264, 4,5,5,5,40,40,0},  // (2,2,2)
  {3344, 4,7,5,5,40,40,0},  // (2,2,3)
  {3456, 4,9,5,5,40,40,0}   // (2,2,4)
};

// Balanced (block, wave) -> k-wave map. Cost c(kw) in {2,4,6,8,10}; every
// row sums to 24. -1 = dummy (wave stages, then exits).
__constant__ short c_kwmap[15][4] = {
  {50,30, 4, 0}, {51,31, 5, 1}, {52,32, 6, 2}, {53,33, 7, 3},
  {54,34,10,-1}, {55,35,11,-1}, {56,36,12,-1},
  {37,43, 8,15}, {44,45, 9,16}, {46,47,17,18}, {48,49,19,20},
  {13,14,21,22}, {23,24,25,26}, {27,28,29,38}, {39,40,41,42}
};

template<int D1, int D2>
__device__ __forceinline__ void load_c(float (&c)[25],
    const float* __restrict__ Crow, int i0, int j0)
{
#pragma unroll
  for (int ii = 0; ii < D1; ++ii)
#pragma unroll
    for (int jj = 0; jj < D2; ++jj)
      c[ii * D2 + jj] = Crow[(i0 + ii) * NF + (j0 + jj)];
}

template<int D1, int D2>
__device__ __forceinline__ void ld_ab(f32x4 (&a)[D1], f32x4 (&b)[D2],
    const float (&f1s)[NF][ZPAD], const float (&f2s)[NF][ZPAD],
    int i0, int j0, int zz)
{
#pragma unroll
  for (int ii = 0; ii < D1; ++ii) a[ii] = *(const f32x4*)&f1s[i0 + ii][zz];
#pragma unroll
  for (int jj = 0; jj < D2; ++jj) b[jj] = *(const f32x4*)&f2s[j0 + jj][zz];
}

template<int D1, int D2>
__device__ __forceinline__ void comp_st(const float (&c)[25],
    const f32x4 (&a)[D1], const f32x4 (&b)[D2], float* __restrict__ opz)
{
#pragma unroll
  for (int q = 0; q < 4; ++q) {
    float acc;
    if constexpr (D1 <= D2) {
      acc = 0.f;
#pragma unroll
      for (int ii = 0; ii < D1; ++ii) {
        float t = c[ii * D2] * b[0][q];
#pragma unroll
        for (int jj = 1; jj < D2; ++jj) t = fmaf(c[ii * D2 + jj], b[jj][q], t);
        acc = fmaf(t, a[ii][q], acc);
      }
    } else {
      acc = 0.f;
#pragma unroll
      for (int jj = 0; jj < D2; ++jj) {
        float t = c[jj] * a[0][q];
#pragma unroll
        for (int ii = 1; ii < D1; ++ii) t = fmaf(c[ii * D2 + jj], a[ii][q], t);
        acc = fmaf(t, b[jj][q], acc);
      }
    }
    __builtin_nontemporal_store(acc, opz + (size_t)q * KTOT);
  }
}

// 2-deep ping-pong pipeline with statically named register sets.
template<int D1, int D2>
__device__ void tp_body(const float (&c)[25], int i0, int j0,
    const float (&f1s)[NF][ZPAD], const float (&f2s)[NF][ZPAD],
    float* __restrict__ op)     // = out + z0*KTOT + k
{
  f32x4 aA[D1], bA[D2], aB[D1], bB[D2];
  ld_ab<D1,D2>(aA, bA, f1s, f2s, i0, j0, 0);
#pragma unroll 1
  for (int zz = 0; zz < ZT; zz += 8) {
    ld_ab<D1,D2>(aB, bB, f1s, f2s, i0, j0, zz + 4);
    comp_st<D1,D2>(c, aA, bA, op + (size_t)zz * KTOT);
    if (zz + 8 < ZT) ld_ab<D1,D2>(aA, bA, f1s, f2s, i0, j0, zz + 8);
    comp_st<D1,D2>(c, aB, bB, op + (size_t)(zz + 4) * KTOT);
  }
}

__global__ __launch_bounds__(BLOCK, 3) void tp_kernel(
    const float* __restrict__ f1, const float* __restrict__ f2,
    const float* __restrict__ M, float* __restrict__ out)
{
  __shared__ __align__(16) float f1s[NF][ZPAD];
  __shared__ __align__(16) float f2s[NF][ZPAD];
  const int z0  = blockIdx.y * ZT;
  const int tid = (int)threadIdx.x;

  // (1) Issue feature-tile staging loads (coalesced float4) into registers.
  const float* f1p = f1 + (size_t)z0 * NF;
  const float* f2p = f2 + (size_t)z0 * NF;
  f32x4 s1[4], s2[4];
#pragma unroll
  for (int r = 0; r < 4; ++r) {
    int t = tid + r * BLOCK;
    if (t < NLD) {
      s1[r] = *(const f32x4*)(f1p + t * 4);
      s2[r] = *(const f32x4*)(f2p + t * 4);
    }
  }

  // (2) Balanced k-wave lookup + branchless segment decode.
  const int wv   = tid >> 6;
  const int lane = tid & 63;
  const int kw   = (int)c_kwmap[blockIdx.x][wv];     // wave-uniform, may be -1
  const int k    = (kw << 6) + lane;
  const bool active = (kw >= 0) && (k < KTOT);
  const int kc = active ? k : 0;
  int s = 0;
  s += (kc >=  256); s += (kc >=  640); s += (kc >=  960); s += (kc >= 1344);
  s += (kc >= 1408); s += (kc >= 1600); s += (kc >= 1920); s += (kc >= 2016);
  s += (kc >= 2176); s += (kc >= 2400); s += (kc >= 2720); s += (kc >= 2816);
  s += (kc >= 2976); s += (kc >= 3200); s += (kc >= 3216); s += (kc >= 3264);
  s += (kc >= 3344); s += (kc >= 3456);
  const Seg sg = c_segs[s];
  const int local = kc - sg.kstart;
  const int uv = local / sg.dl;
  const int u  = uv / sg.mul2;
  const int v  = uv - u * sg.mul2;
  const int i0 = sg.ioff + u * sg.d1;
  const int j0 = sg.joff + v * sg.d2;
  const float* Crow = M + (size_t)kc * (NF * NF);

  // (3) Issue c[] loads NOW — latency rides through ds_write + barrier.
  float c[25];
  const int d1 = sg.d1, d2 = sg.d2;
  if (d1 == 1) {
    if (d2 == 1)      load_c<1,1>(c, Crow, i0, j0);
    else if (d2 == 3) load_c<1,3>(c, Crow, i0, j0);
    else              load_c<1,5>(c, Crow, i0, j0);
  } else if (d1 == 3) {
    if (d2 == 1)      load_c<3,1>(c, Crow, i0, j0);
    else if (d2 == 3) load_c<3,3>(c, Crow, i0, j0);
    else              load_c<3,5>(c, Crow, i0, j0);
  } else {
    if (d2 == 1)      load_c<5,1>(c, Crow, i0, j0);
    else if (d2 == 3) load_c<5,3>(c, Crow, i0, j0);
    else              load_c<5,5>(c, Crow, i0, j0);
  }

  // (4) Transposed LDS write (feature-major): f1s[f][z].
#pragma unroll
  for (int r = 0; r < 4; ++r) {
    int t = tid + r * BLOCK;
    if (t < NLD) {
      int g = t * 4, zz = g / NF, f0 = g % NF;
      f1s[f0 + 0][zz] = s1[r][0]; f1s[f0 + 1][zz] = s1[r][1];
      f1s[f0 + 2][zz] = s1[r][2]; f1s[f0 + 3][zz] = s1[r][3];
      f2s[f0 + 0][zz] = s2[r][0]; f2s[f0 + 1][zz] = s2[r][1];
      f2s[f0 + 2][zz] = s2[r][2]; f2s[f0 + 3][zz] = s2[r][3];
    }
  }
  __syncthreads();

  if (!active) return;
  float* op = out + (size_t)z0 * KTOT + k;

  if (d1 == 1) {
    if (d2 == 1)      tp_body<1,1>(c, i0, j0, f1s, f2s, op);
    else if (d2 == 3) tp_body<1,3>(c, i0, j0, f1s, f2s, op);
    else              tp_body<1,5>(c, i0, j0, f1s, f2s, op);
  } else if (d1 == 3) {
    if (d2 == 1)      tp_body<3,1>(c, i0, j0, f1s, f2s, op);
    else if (d2 == 3) tp_body<3,3>(c, i0, j0, f1s, f2s, op);
    else              tp_body<3,5>(c, i0, j0, f1s, f2s, op);
  } else {
    if (d2 == 1)      tp_body<5,1>(c, i0, j0, f1s, f2s, op);
    else if (d2 == 3) tp_body<5,3>(c, i0, j0, f1s, f2s, op);
    else              tp_body<5,5>(c, i0, j0, f1s, f2s, op);
  }
}

extern "C" void kernel_launch(void* const* d_in, const int* in_sizes, int n_in,
                              void* d_out, int out_size, void* d_ws, size_t ws_size,
                              hipStream_t stream) {
  const float* f1 = (const float*)d_in[0];
  const float* f2 = (const float*)d_in[1];
  const float* M  = (const float*)d_in[2];
  float* out = (float*)d_out;

  const int Z = in_sizes[0] / NF;        // 4096
  dim3 grid(15, Z / ZT);                 // 15 x 64
  tp_kernel<<<grid, dim3(BLOCK), 0, stream>>>(f1, f2, M, out);
}